// Round 1
// baseline (1366.278 us; speedup 1.0000x reference)
//
#include <hip/hip_runtime.h>

#define B_    2
#define L_    1024
#define D_    768
#define H_    12
#define DH_   64
#define DP_   32
#define MLP_  3072
#define NL_   4
#define WIN_  128
#define W2_   257            // window columns (rel = j-i+128 in [0,256])
#define M_    (B_*L_)        // 2048 rows

typedef __attribute__((ext_vector_type(8))) short bf16x8;
typedef __attribute__((ext_vector_type(4))) float f32x4;

__device__ __forceinline__ unsigned short f2bf(float x){
  unsigned int u = __float_as_uint(x);
  u += 0x7fffu + ((u >> 16) & 1u);   // RNE; inputs finite
  return (unsigned short)(u >> 16);
}

__device__ __forceinline__ void gl_lds16(const void* g, void* l){
  __builtin_amdgcn_global_load_lds((__attribute__((address_space(1))) void*)g,
                                   (__attribute__((address_space(3))) void*)l, 16, 0, 0);
}

// ---------------- f32 -> bf16 weight conversion ----------------
__global__ __launch_bounds__(256) void cvt_bf16_k(const float* __restrict__ src,
                                                  unsigned short* __restrict__ dst, int n4){
  int i = blockIdx.x*256 + threadIdx.x;
  if (i >= n4) return;
  float4 v = ((const float4*)src)[i];
  ushort4 o;
  o.x = f2bf(v.x); o.y = f2bf(v.y); o.z = f2bf(v.z); o.w = f2bf(v.w);
  ((ushort4*)dst)[i] = o;
}

// ---------------- pair bias: LN(pair)@pb_w + pb_b for ALL layers, window only ----
__global__ __launch_bounds__(256) void pair_bias_k(const float* __restrict__ pair,
    const float* __restrict__ ln_g, const float* __restrict__ ln_b,
    const float* __restrict__ pb_w, const float* __restrict__ pb_b,
    float* __restrict__ bias){
  __shared__ float gw[NL_][DP_];
  __shared__ float cb[NL_];
  int tid = threadIdx.x;
  if (tid < NL_*DP_) gw[tid>>5][tid&31] = ln_g[tid]*pb_w[tid];
  if (tid < NL_){
    float c = 0.f;
    for (int d=0; d<DP_; ++d) c += ln_b[tid*DP_+d]*pb_w[tid*DP_+d];
    cb[tid] = c + pb_b[tid];
  }
  __syncthreads();
  int idx = blockIdx.x*256 + tid;
  if (idx >= B_*L_*W2_) return;
  int rel = idx % W2_;
  int t   = idx / W2_;
  int i   = t & (L_-1);
  int b   = t >> 10;
  int j   = i + rel - WIN_;
  if (j < 0 || j >= L_) return;            // never read by attention
  const float4* p = (const float4*)(pair + ((size_t)(b*L_ + i)*L_ + j)*DP_);
  float4 x[8];
  #pragma unroll
  for (int q=0;q<8;++q) x[q] = p[q];
  float s=0.f, ss=0.f;
  #pragma unroll
  for (int q=0;q<8;++q){
    s  += x[q].x + x[q].y + x[q].z + x[q].w;
    ss += x[q].x*x[q].x + x[q].y*x[q].y + x[q].z*x[q].z + x[q].w*x[q].w;
  }
  float m  = s * (1.0f/DP_);
  float rs = rsqrtf(ss*(1.0f/DP_) - m*m + 1e-5f);
  #pragma unroll
  for (int l=0;l<NL_;++l){
    float acc = 0.f;
    #pragma unroll
    for (int q=0;q<8;++q){
      acc += (x[q].x-m)*gw[l][4*q+0] + (x[q].y-m)*gw[l][4*q+1]
           + (x[q].z-m)*gw[l][4*q+2] + (x[q].w-m)*gw[l][4*q+3];
    }
    bias[(((size_t)l*B_ + b)*L_ + i)*W2_ + rel] = acc*rs + cb[l];
  }
}

// ---------------- rmsnorm: s[M,768] f32 -> h bf16 ----------------
__global__ __launch_bounds__(256) void rmsnorm_k(const float* __restrict__ s,
                                                 unsigned short* __restrict__ h){
  int row = blockIdx.x, tid = threadIdx.x;
  const float* x = s + (size_t)row*D_;
  float v0 = x[tid], v1 = x[tid+256], v2 = x[tid+512];
  float ss = v0*v0 + v1*v1 + v2*v2;
  #pragma unroll
  for (int m=1; m<64; m<<=1) ss += __shfl_xor(ss, m, 64);
  __shared__ float wsum[4];
  __shared__ float rbuf;
  if ((tid & 63) == 0) wsum[tid>>6] = ss;
  __syncthreads();
  if (tid == 0) rbuf = rsqrtf((wsum[0]+wsum[1]+wsum[2]+wsum[3])*(1.0f/D_) + 1.1920929e-07f);
  __syncthreads();
  float r = rbuf;
  unsigned short* o = h + (size_t)row*D_;
  o[tid]     = f2bf(v0*r);
  o[tid+256] = f2bf(v1*r);
  o[tid+512] = f2bf(v2*r);
}

// ---------------- bf16 GEMM: C[M,N] = A[M,K] @ W[N,K]^T + bias, fused epilogues ----
// MODE 0: outf = C            (qkv)
// MODE 1: resid += C          (attn out proj, N=768)
// MODE 2: outb = bf16(gelu(C))(fc1)
// MODE 3: resid += C          (fc2, N=768)
template<int MODE>
__global__ __launch_bounds__(256) void gemm_bt(const unsigned short* __restrict__ A,
    const unsigned short* __restrict__ W, const float* __restrict__ bias,
    float* __restrict__ outf, unsigned short* __restrict__ outb,
    float* __restrict__ resid, int N, int K){
  __shared__ short As[128*32];
  __shared__ short Bs[128*32];
  const int tid  = threadIdx.x;
  const int wave = tid >> 6, lane = tid & 63;
  const int m0 = blockIdx.y << 7, n0 = blockIdx.x << 7;
  const int wm = (wave >> 1) << 6, wn = (wave & 1) << 6;
  const int lrow = lane & 15, ko = (lane >> 4) << 3;
  f32x4 acc[4][4] = {};
  const int r0 = tid >> 2, kc0 = (tid & 3) << 3;
  const unsigned short* Ag = A + (size_t)(m0 + r0)*K + kc0;
  const unsigned short* Wg = W + (size_t)(n0 + r0)*K + kc0;
  const size_t half = (size_t)64*K;
  for (int kt = 0; kt < K; kt += 32){
    __syncthreads();
    gl_lds16(Ag + kt,        &As[tid*8]);
    gl_lds16(Ag + half + kt, &As[(tid+256)*8]);
    gl_lds16(Wg + kt,        &Bs[tid*8]);
    gl_lds16(Wg + half + kt, &Bs[(tid+256)*8]);
    __syncthreads();
    bf16x8 af[4], bv[4];
    #pragma unroll
    for (int i=0;i<4;++i) af[i] = *(const bf16x8*)&As[((wm + i*16 + lrow) << 5) + ko];
    #pragma unroll
    for (int i=0;i<4;++i) bv[i] = *(const bf16x8*)&Bs[((wn + i*16 + lrow) << 5) + ko];
    #pragma unroll
    for (int mi=0;mi<4;++mi)
      #pragma unroll
      for (int ni=0;ni<4;++ni)
        acc[mi][ni] = __builtin_amdgcn_mfma_f32_16x16x32_bf16(af[mi], bv[ni], acc[mi][ni], 0, 0, 0);
  }
  #pragma unroll
  for (int ni=0;ni<4;++ni){
    const int col = n0 + wn + ni*16 + lrow;
    const float bb = bias[col];
    #pragma unroll
    for (int mi=0;mi<4;++mi){
      const int rw = m0 + wm + mi*16 + ((lane >> 4) << 2);
      #pragma unroll
      for (int r=0;r<4;++r){
        float v = acc[mi][ni][r] + bb;
        if (MODE == 0){
          outf[(size_t)(rw + r)*N + col] = v;
        } else if (MODE == 2){
          float g = 0.5f * v * (1.0f + erff(v * 0.70710678118654752f));
          outb[(size_t)(rw + r)*N + col] = f2bf(g);
        } else {
          resid[(size_t)(rw + r)*D_ + col] += v;
        }
      }
    }
  }
}

// ---------------- rope + pack qkv f32 [M,2304] -> q_r,k_r,v_r [B*H, L, 64] f32 ----
__global__ __launch_bounds__(256) void rope_k(const float* __restrict__ qkv,
    float* __restrict__ qr, float* __restrict__ kr, float* __restrict__ vr){
  int idx = blockIdx.x*256 + threadIdx.x;        // = (bh*L + i)*64 + d, exact grid
  int d  = idx & 63;
  int r  = idx >> 6;
  int i  = r & (L_-1);
  int bh = r >> 10;                              // 0..23
  int b  = bh / H_, h = bh - (bh / H_)*H_;
  const float* base = qkv + ((size_t)(b*L_ + i))*(3*D_) + h*64 + d;
  float qv = base[0], kv = base[D_], vv = base[2*D_];
  int t = d & 31;
  float invf = expf(-(float)t * 0.28782313662425572f);   // ln(10000)/32
  float ang = (float)i * invf;
  float sn, cs;
  sincosf(ang, &sn, &cs);
  float pq = (d < 32) ? -base[32]      : base[-32];
  float pk = (d < 32) ? -base[D_+32-32+32] : base[D_-32]; // fixed below
  pk = (d < 32) ? -base[D_+32] : base[D_-32];
  qr[idx] = qv*cs + pq*sn;
  kr[idx] = kv*cs + pk*sn;
  vr[idx] = vv;
}

// ---------------- windowed attention, f32 vector, 16-query tiles ----------------
__global__ __launch_bounds__(256) void attn_k(const float* __restrict__ qr,
    const float* __restrict__ kr, const float* __restrict__ vr,
    const float* __restrict__ bias, unsigned short* __restrict__ ybf, int layer){
  __shared__ float q_s[16][68];
  __shared__ float kv_s[16][68];
  __shared__ float sc_s[16][273];
  const int tid = threadIdx.x;
  const int qq = tid >> 4, tj = tid & 15;
  const int bh = blockIdx.y;
  const int b = bh / H_, h = bh - b*H_;
  const int i0 = blockIdx.x * 16;
  const int jb = i0 - WIN_;
  *(float4*)&q_s[qq][tj*4] =
      *(const float4*)(qr + ((size_t)bh*L_ + i0 + qq)*64 + tj*4);
  const float* brow = bias + (((size_t)(layer*B_ + b))*L_ + i0 + qq)*W2_;
  for (int c=0;c<17;++c){
    __syncthreads();
    int j = jb + c*16 + qq;
    float4 kvv = make_float4(0.f,0.f,0.f,0.f);
    if (j >= 0 && j < L_) kvv = *(const float4*)(kr + ((size_t)bh*L_ + j)*64 + tj*4);
    *(float4*)&kv_s[qq][tj*4] = kvv;
    __syncthreads();
    int jj = c*16 + tj;
    int rel = jj - qq;
    int jg = jb + jj;
    float sc = -1e30f;
    if (rel >= 0 && rel <= 256 && jg >= 0 && jg < L_){
      float dot = 0.f;
      #pragma unroll
      for (int d4=0; d4<16; ++d4){
        float4 a = *(const float4*)&q_s[qq][d4*4];
        float4 k4 = *(const float4*)&kv_s[tj][d4*4];
        dot += a.x*k4.x + a.y*k4.y + a.z*k4.z + a.w*k4.w;
      }
      sc = dot*0.125f + brow[rel];
    }
    sc_s[qq][jj] = sc;
  }
  __syncthreads();
  float mx = -3.0e38f;
  for (int c=0;c<17;++c) mx = fmaxf(mx, sc_s[qq][c*16+tj]);
  #pragma unroll
  for (int m=1; m<16; m<<=1) mx = fmaxf(mx, __shfl_xor(mx, m, 16));
  float sm = 0.f;
  for (int c=0;c<17;++c){
    int jj = c*16 + tj;
    float e = __expf(sc_s[qq][jj] - mx);
    sc_s[qq][jj] = e;
    sm += e;
  }
  #pragma unroll
  for (int m=1; m<16; m<<=1) sm += __shfl_xor(sm, m, 16);
  float inv = 1.0f / sm;
  float o0=0.f, o1=0.f, o2=0.f, o3=0.f;
  for (int c=0;c<17;++c){
    __syncthreads();
    int j = jb + c*16 + qq;
    float4 vvv = make_float4(0.f,0.f,0.f,0.f);
    if (j >= 0 && j < L_) vvv = *(const float4*)(vr + ((size_t)bh*L_ + j)*64 + tj*4);
    *(float4*)&kv_s[qq][tj*4] = vvv;
    __syncthreads();
    #pragma unroll
    for (int jl=0; jl<16; ++jl){
      float p = sc_s[qq][c*16 + jl];
      o0 += p * kv_s[jl][tj];
      o1 += p * kv_s[jl][tj+16];
      o2 += p * kv_s[jl][tj+32];
      o3 += p * kv_s[jl][tj+48];
    }
  }
  size_t ob = ((size_t)(b*L_ + i0 + qq))*D_ + h*64 + tj;
  ybf[ob]      = f2bf(o0*inv);
  ybf[ob+16]   = f2bf(o1*inv);
  ybf[ob+32]   = f2bf(o2*inv);
  ybf[ob+48]   = f2bf(o3*inv);
}

extern "C" void kernel_launch(void* const* d_in, const int* in_sizes, int n_in,
                              void* d_out, int out_size, void* d_ws, size_t ws_size,
                              hipStream_t stream){
  (void)in_sizes; (void)n_in; (void)out_size; (void)ws_size;
  const float* s_in  = (const float*)d_in[0];
  const float* pair  = (const float*)d_in[1];
  const float* qkv_w = (const float*)d_in[2];
  const float* qkv_b = (const float*)d_in[3];
  const float* out_w = (const float*)d_in[4];
  const float* out_b = (const float*)d_in[5];
  const float* fc1_w = (const float*)d_in[6];
  const float* fc1_b = (const float*)d_in[7];
  const float* fc2_w = (const float*)d_in[8];
  const float* fc2_b = (const float*)d_in[9];
  const float* ln_g  = (const float*)d_in[10];
  const float* ln_b  = (const float*)d_in[11];
  const float* pb_w  = (const float*)d_in[12];
  const float* pb_b  = (const float*)d_in[13];
  float* s = (float*)d_out;                    // residual stream lives in d_out

  char* ws = (char*)d_ws;
  size_t off = 0;
  auto take = [&](size_t bytes)->char*{
    char* p = ws + off; off += (bytes + 255) & ~(size_t)255; return p;
  };
  unsigned short* wqkv = (unsigned short*)take((size_t)NL_*3*D_*D_*2);
  unsigned short* wout = (unsigned short*)take((size_t)NL_*D_*D_*2);
  unsigned short* wfc1 = (unsigned short*)take((size_t)NL_*MLP_*D_*2);
  unsigned short* wfc2 = (unsigned short*)take((size_t)NL_*D_*MLP_*2);
  float*          bw   = (float*)take((size_t)NL_*B_*L_*W2_*4);
  unsigned short* hbf  = (unsigned short*)take((size_t)M_*D_*2);
  float*          qkvf = (float*)take((size_t)M_*3*D_*4);
  float*          q_r  = (float*)take((size_t)B_*H_*L_*DH_*4);
  float*          k_r  = (float*)take((size_t)B_*H_*L_*DH_*4);
  float*          v_r  = (float*)take((size_t)B_*H_*L_*DH_*4);
  unsigned short* ybf  = (unsigned short*)take((size_t)M_*D_*2);
  unsigned short* gbf  = (unsigned short*)take((size_t)M_*MLP_*2);

  hipMemcpyAsync(s, s_in, (size_t)M_*D_*sizeof(float), hipMemcpyDeviceToDevice, stream);

  auto cvt = [&](const float* src, unsigned short* dst, size_t n){
    int n4 = (int)(n/4);
    cvt_bf16_k<<<(n4+255)/256, 256, 0, stream>>>(src, dst, n4);
  };
  cvt(qkv_w, wqkv, (size_t)NL_*3*D_*D_);
  cvt(out_w, wout, (size_t)NL_*D_*D_);
  cvt(fc1_w, wfc1, (size_t)NL_*MLP_*D_);
  cvt(fc2_w, wfc2, (size_t)NL_*D_*MLP_);

  pair_bias_k<<<(B_*L_*W2_ + 255)/256, 256, 0, stream>>>(pair, ln_g, ln_b, pb_w, pb_b, bw);

  for (int l=0; l<NL_; ++l){
    rmsnorm_k<<<M_, 256, 0, stream>>>(s, hbf);
    gemm_bt<0><<<dim3((3*D_)/128, M_/128), 256, 0, stream>>>(
        hbf, wqkv + (size_t)l*3*D_*D_, qkv_b + l*3*D_, qkvf, nullptr, nullptr, 3*D_, D_);
    rope_k<<<(B_*H_*L_*DH_)/256, 256, 0, stream>>>(qkvf, q_r, k_r, v_r);
    attn_k<<<dim3(L_/16, B_*H_), 256, 0, stream>>>(q_r, k_r, v_r, bw, ybf, l);
    gemm_bt<1><<<dim3(D_/128, M_/128), 256, 0, stream>>>(
        ybf, wout + (size_t)l*D_*D_, out_b + l*D_, nullptr, nullptr, s, D_, D_);
    rmsnorm_k<<<M_, 256, 0, stream>>>(s, hbf);
    gemm_bt<2><<<dim3(MLP_/128, M_/128), 256, 0, stream>>>(
        hbf, wfc1 + (size_t)l*MLP_*D_, fc1_b + l*MLP_, nullptr, gbf, nullptr, MLP_, D_);
    gemm_bt<3><<<dim3(D_/128, M_/128), 256, 0, stream>>>(
        gbf, wfc2 + (size_t)l*D_*MLP_, fc2_b + l*D_, nullptr, nullptr, s, D_, MLP_);
  }
}

// Round 2
// 1039.547 us; speedup vs baseline: 1.3143x; 1.3143x over previous
//
#include <hip/hip_runtime.h>

#define B_    2
#define L_    1024
#define D_    768
#define H_    12
#define DH_   64
#define DP_   32
#define MLP_  3072
#define NL_   4
#define WIN_  128
#define W2_   257            // window columns (rel = j-i+128 in [0,256])
#define M_    (B_*L_)        // 2048 rows

typedef __attribute__((ext_vector_type(8))) short bf16x8;
typedef __attribute__((ext_vector_type(4))) float f32x4;

__device__ __forceinline__ unsigned short f2bf(float x){
  unsigned int u = __float_as_uint(x);
  u += 0x7fffu + ((u >> 16) & 1u);   // RNE; inputs finite
  return (unsigned short)(u >> 16);
}

__device__ __forceinline__ void gl_lds16(const void* g, void* l){
  __builtin_amdgcn_global_load_lds((__attribute__((address_space(1))) void*)g,
                                   (__attribute__((address_space(3))) void*)l, 16, 0, 0);
}

// ---------------- f32 -> bf16 weight conversion ----------------
__global__ __launch_bounds__(256) void cvt_bf16_k(const float* __restrict__ src,
                                                  unsigned short* __restrict__ dst, int n4){
  int i = blockIdx.x*256 + threadIdx.x;
  if (i >= n4) return;
  float4 v = ((const float4*)src)[i];
  ushort4 o;
  o.x = f2bf(v.x); o.y = f2bf(v.y); o.z = f2bf(v.z); o.w = f2bf(v.w);
  ((ushort4*)dst)[i] = o;
}

// ---------------- pair bias: LN(pair)@pb_w + pb_b for ALL layers, window only ----
__global__ __launch_bounds__(256) void pair_bias_k(const float* __restrict__ pair,
    const float* __restrict__ ln_g, const float* __restrict__ ln_b,
    const float* __restrict__ pb_w, const float* __restrict__ pb_b,
    float* __restrict__ bias){
  __shared__ float gw[NL_][DP_];
  __shared__ float cb[NL_];
  int tid = threadIdx.x;
  if (tid < NL_*DP_) gw[tid>>5][tid&31] = ln_g[tid]*pb_w[tid];
  if (tid < NL_){
    float c = 0.f;
    for (int d=0; d<DP_; ++d) c += ln_b[tid*DP_+d]*pb_w[tid*DP_+d];
    cb[tid] = c + pb_b[tid];
  }
  __syncthreads();
  int idx = blockIdx.x*256 + tid;
  if (idx >= B_*L_*W2_) return;
  int rel = idx % W2_;
  int t   = idx / W2_;
  int i   = t & (L_-1);
  int b   = t >> 10;
  int j   = i + rel - WIN_;
  if (j < 0 || j >= L_) return;            // never read by attention
  const float4* p = (const float4*)(pair + ((size_t)(b*L_ + i)*L_ + j)*DP_);
  float4 x[8];
  #pragma unroll
  for (int q=0;q<8;++q) x[q] = p[q];
  float s=0.f, ss=0.f;
  #pragma unroll
  for (int q=0;q<8;++q){
    s  += x[q].x + x[q].y + x[q].z + x[q].w;
    ss += x[q].x*x[q].x + x[q].y*x[q].y + x[q].z*x[q].z + x[q].w*x[q].w;
  }
  float m  = s * (1.0f/DP_);
  float rs = rsqrtf(ss*(1.0f/DP_) - m*m + 1e-5f);
  #pragma unroll
  for (int l=0;l<NL_;++l){
    float acc = 0.f;
    #pragma unroll
    for (int q=0;q<8;++q){
      acc += (x[q].x-m)*gw[l][4*q+0] + (x[q].y-m)*gw[l][4*q+1]
           + (x[q].z-m)*gw[l][4*q+2] + (x[q].w-m)*gw[l][4*q+3];
    }
    bias[(((size_t)l*B_ + b)*L_ + i)*W2_ + rel] = acc*rs + cb[l];
  }
}

// ---------------- rmsnorm: s[M,768] f32 -> h bf16 ----------------
__global__ __launch_bounds__(256) void rmsnorm_k(const float* __restrict__ s,
                                                 unsigned short* __restrict__ h){
  int row = blockIdx.x, tid = threadIdx.x;
  const float* x = s + (size_t)row*D_;
  float v0 = x[tid], v1 = x[tid+256], v2 = x[tid+512];
  float ss = v0*v0 + v1*v1 + v2*v2;
  #pragma unroll
  for (int m=1; m<64; m<<=1) ss += __shfl_xor(ss, m, 64);
  __shared__ float wsum[4];
  __shared__ float rbuf;
  if ((tid & 63) == 0) wsum[tid>>6] = ss;
  __syncthreads();
  if (tid == 0) rbuf = rsqrtf((wsum[0]+wsum[1]+wsum[2]+wsum[3])*(1.0f/D_) + 1.1920929e-07f);
  __syncthreads();
  float r = rbuf;
  unsigned short* o = h + (size_t)row*D_;
  o[tid]     = f2bf(v0*r);
  o[tid+256] = f2bf(v1*r);
  o[tid+512] = f2bf(v2*r);
}

// ---------------- bf16 GEMM: C[M,N] = A[M,K] @ W[N,K]^T + bias, fused epilogues ----
// MODE 0: outf = C            (qkv)
// MODE 1: resid += C          (attn out proj)
// MODE 2: outb = bf16(gelu(C))(fc1)
// MODE 3: resid += C          (fc2)
// TM: 128 or 64 (M rows per block). SPLIT: split-K factor (atomicAdd epilogue if >1).
template<int MODE, int TM, int SPLIT>
__global__ __launch_bounds__(256) void gemm_bt(const unsigned short* __restrict__ A,
    const unsigned short* __restrict__ W, const float* __restrict__ bias,
    float* __restrict__ outf, unsigned short* __restrict__ outb,
    float* __restrict__ resid, int N, int K){
  constexpr int MI = TM/32;
  __shared__ __align__(16) short sm[2][(TM+128)*32];
  const int tid  = threadIdx.x;
  const int wave = tid >> 6, lane = tid & 63;
  const int m0 = blockIdx.y*TM, n0 = blockIdx.x << 7;
  const int KB = K / SPLIT;
  const int kbase = blockIdx.z * KB;
  const int wm = (wave >> 1)*(TM/2), wn = (wave & 1) << 6;
  const int lrow = lane & 15, ko = (lane >> 4) << 3;
  f32x4 acc[MI][4] = {};
  const unsigned short* Ag = A + (size_t)(m0 + (tid>>2))*K + kbase + ((tid&3)<<3);
  const unsigned short* Wg = W + (size_t)(n0 + (tid>>2))*K + kbase + ((tid&3)<<3);
  const size_t hstep = (size_t)64*K;
  const int nk = KB >> 5;
  {  // prologue stage into buf 0
    short* As = sm[0]; short* Bs = sm[0] + TM*32;
    gl_lds16(Ag, &As[tid*8]);
    if (TM == 128) gl_lds16(Ag + hstep, &As[(tid+256)*8]);
    gl_lds16(Wg, &Bs[tid*8]);
    gl_lds16(Wg + hstep, &Bs[(tid+256)*8]);
  }
  for (int it = 0; it < nk; ++it){
    __syncthreads();                       // drains vmcnt -> buf (it&1) ready
    if (it + 1 < nk){                      // async-prefetch next tile, overlaps MFMA below
      short* As = sm[(it&1)^1]; short* Bs = As + TM*32;
      const int kt = (it+1) << 5;
      gl_lds16(Ag + kt, &As[tid*8]);
      if (TM == 128) gl_lds16(Ag + hstep + kt, &As[(tid+256)*8]);
      gl_lds16(Wg + kt, &Bs[tid*8]);
      gl_lds16(Wg + hstep + kt, &Bs[(tid+256)*8]);
    }
    const short* As = sm[it&1]; const short* Bs = As + TM*32;
    bf16x8 af[MI], bv[4];
    #pragma unroll
    for (int i=0;i<MI;++i) af[i] = *(const bf16x8*)&As[((wm + i*16 + lrow) << 5) + ko];
    #pragma unroll
    for (int i=0;i<4;++i)  bv[i] = *(const bf16x8*)&Bs[((wn + i*16 + lrow) << 5) + ko];
    #pragma unroll
    for (int mi=0;mi<MI;++mi)
      #pragma unroll
      for (int ni=0;ni<4;++ni)
        acc[mi][ni] = __builtin_amdgcn_mfma_f32_16x16x32_bf16(af[mi], bv[ni], acc[mi][ni], 0, 0, 0);
  }
  #pragma unroll
  for (int ni=0;ni<4;++ni){
    const int col = n0 + wn + ni*16 + lrow;
    const float bb = (SPLIT == 1 || blockIdx.z == 0) ? bias[col] : 0.f;
    #pragma unroll
    for (int mi=0;mi<MI;++mi){
      const int rw = m0 + wm + mi*16 + ((lane >> 4) << 2);
      #pragma unroll
      for (int r=0;r<4;++r){
        float v = acc[mi][ni][r] + bb;
        if (MODE == 0){
          outf[(size_t)(rw + r)*N + col] = v;
        } else if (MODE == 2){
          float g = 0.5f * v * (1.0f + erff(v * 0.70710678118654752f));
          outb[(size_t)(rw + r)*N + col] = f2bf(g);
        } else {
          if (SPLIT == 1) resid[(size_t)(rw + r)*D_ + col] += v;
          else            atomicAdd(&resid[(size_t)(rw + r)*D_ + col], v);
        }
      }
    }
  }
}

// ---------------- rope: qkv f32 [M,2304] -> q_r,k_r [B*H, L, 64] f32 ----
__global__ __launch_bounds__(256) void rope_k(const float* __restrict__ qkv,
    float* __restrict__ qr, float* __restrict__ kr){
  int idx = blockIdx.x*256 + threadIdx.x;
  int d  = idx & 63;
  int r  = idx >> 6;
  int i  = r & (L_-1);
  int bh = r >> 10;
  int b  = bh / H_, h = bh - (bh / H_)*H_;
  const float* base = qkv + ((size_t)(b*L_ + i))*(3*D_) + h*64 + d;
  float qv = base[0], kv = base[D_];
  int t = d & 31;
  float invf = expf(-(float)t * 0.28782313662425572f);   // ln(10000)/32
  float ang = (float)i * invf;
  float sn, cs;
  sincosf(ang, &sn, &cs);
  float pq = (d < 32) ? -base[32]    : base[-32];
  float pk = (d < 32) ? -base[D_+32] : base[D_-32];
  qr[idx] = qv*cs + pq*sn;
  kr[idx] = kv*cs + pk*sn;
}

// ---------------- windowed MFMA attention, 16-query tiles ----------------
// Per block: one (bh, 16-query tile). K-strip of 288 keys staged bf16 in LDS,
// QK^T and PV via 16x16x32 bf16 MFMA. V reuses the K buffer after softmax.
__global__ __launch_bounds__(256) void attn_k(const float* __restrict__ qr,
    const float* __restrict__ kr, const float* __restrict__ qkvf,
    const float* __restrict__ bias, unsigned short* __restrict__ ybf, int layer){
  __shared__ __align__(16) short kb[288*72];   // K then V, row stride 72 (+8 pad)
  __shared__ __align__(16) float sc[16*304];   // scores f32; probs bf16 alias below
  short* ps = (short*)sc;                      // [16][288] bf16, stride 288
  const int tid  = threadIdx.x;
  const int wave = tid >> 6, lane = tid & 63;
  const int quad = lane >> 4, lrow = lane & 15;
  const int bh = blockIdx.y, b = bh / H_, h = bh - b*H_;
  const int i0 = blockIdx.x * 16, jb = i0 - WIN_;

  // Q fragments: A[m=lrow][k=quad*8+j], two K=32 halves
  bf16x8 qf0, qf1;
  {
    const float* qrow = qr + ((size_t)bh*L_ + i0 + lrow)*64 + quad*8;
    #pragma unroll
    for (int j=0;j<8;++j) qf0[j] = (short)f2bf(qrow[j]);
    #pragma unroll
    for (int j=0;j<8;++j) qf1[j] = (short)f2bf(qrow[32+j]);
  }
  // stage K strip (288 rows x 64) as bf16, zero-filled outside [0,L)
  {
    const int seg = tid & 3;
    for (int r = tid>>2; r < 288; r += 64){
      int jg = jb + r;
      short* dst = &kb[r*72 + seg*16];
      if (jg >= 0 && jg < L_){
        const float4* sp = (const float4*)(kr + ((size_t)bh*L_ + jg)*64 + seg*16);
        #pragma unroll
        for (int i=0;i<4;++i){
          float4 x = sp[i];
          short o0 = (short)f2bf(x.x), o1 = (short)f2bf(x.y);
          short o2 = (short)f2bf(x.z), o3 = (short)f2bf(x.w);
          dst[i*4+0]=o0; dst[i*4+1]=o1; dst[i*4+2]=o2; dst[i*4+3]=o3;
        }
      } else {
        #pragma unroll
        for (int i=0;i<16;++i) dst[i] = 0;
      }
    }
  }
  __syncthreads();
  // QK^T: 18 chunks of 16 keys, round-robin over waves
  for (int c = wave; c < 18; c += 4){
    const int krow = c*16 + lrow;
    bf16x8 kf0 = *(const bf16x8*)&kb[krow*72 + quad*8];
    bf16x8 kf1 = *(const bf16x8*)&kb[krow*72 + 32 + quad*8];
    f32x4 z = {0.f,0.f,0.f,0.f};
    f32x4 cc = __builtin_amdgcn_mfma_f32_16x16x32_bf16(qf0, kf0, z, 0, 0, 0);
    cc = __builtin_amdgcn_mfma_f32_16x16x32_bf16(qf1, kf1, cc, 0, 0, 0);
    const int jj = c*16 + lrow, jg = jb + jj;
    #pragma unroll
    for (int r=0;r<4;++r){
      const int row = quad*4 + r;
      const int rel = jj - row;
      float v = -1e30f;
      if (rel >= 0 && rel <= 256 && jg >= 0 && jg < L_)
        v = cc[r]*0.125f + bias[(((size_t)(layer*B_ + b))*L_ + i0 + row)*W2_ + rel];
      sc[row*304 + jj] = v;
    }
  }
  __syncthreads();
  // softmax per row (qq), 16 cols per thread group
  const int qq = tid >> 4, tj = tid & 15;
  float ev[18];
  #pragma unroll
  for (int c=0;c<18;++c) ev[c] = sc[qq*304 + c*16 + tj];
  __syncthreads();                 // all sc reads done before ps alias-writes
  float mx = -3.0e38f;
  #pragma unroll
  for (int c=0;c<18;++c) mx = fmaxf(mx, ev[c]);
  #pragma unroll
  for (int m=1; m<16; m<<=1) mx = fmaxf(mx, __shfl_xor(mx, m, 16));
  float sm = 0.f;
  #pragma unroll
  for (int c=0;c<18;++c){ float e = __expf(ev[c] - mx); ev[c] = e; sm += e; }
  #pragma unroll
  for (int m=1; m<16; m<<=1) sm += __shfl_xor(sm, m, 16);
  const float inv = 1.0f / sm;
  #pragma unroll
  for (int c=0;c<18;++c) ps[qq*288 + c*16 + tj] = (short)f2bf(ev[c]*inv);
  // stage V into kb (V needs zero-fill: ps=0 rows must not meet inf/NaN)
  {
    const int seg = tid & 3;
    for (int r = tid>>2; r < 288; r += 64){
      int jg = jb + r;
      short* dst = &kb[r*72 + seg*16];
      if (jg >= 0 && jg < L_){
        const float4* sp = (const float4*)(qkvf + ((size_t)(b*L_ + jg))*2304 + 1536 + h*64 + seg*16);
        #pragma unroll
        for (int i=0;i<4;++i){
          float4 x = sp[i];
          short o0 = (short)f2bf(x.x), o1 = (short)f2bf(x.y);
          short o2 = (short)f2bf(x.z), o3 = (short)f2bf(x.w);
          dst[i*4+0]=o0; dst[i*4+1]=o1; dst[i*4+2]=o2; dst[i*4+3]=o3;
        }
      } else {
        #pragma unroll
        for (int i=0;i<16;++i) dst[i] = 0;
      }
    }
  }
  __syncthreads();
  // PV: O[16][64] = P[16x288] @ V[288x64]; wave owns d-tile [wave*16, wave*16+16)
  f32x4 o = {0.f,0.f,0.f,0.f};
  for (int kc=0; kc<9; ++kc){
    bf16x8 af = *(const bf16x8*)&ps[lrow*288 + kc*32 + quad*8];
    bf16x8 bf;
    #pragma unroll
    for (int j=0;j<8;++j) bf[j] = kb[(kc*32 + quad*8 + j)*72 + wave*16 + lrow];
    o = __builtin_amdgcn_mfma_f32_16x16x32_bf16(af, bf, o, 0, 0, 0);
  }
  #pragma unroll
  for (int r=0;r<4;++r){
    const int row = quad*4 + r;
    ybf[((size_t)(b*L_ + i0 + row))*D_ + h*64 + wave*16 + lrow] = f2bf(o[r]);
  }
}

extern "C" void kernel_launch(void* const* d_in, const int* in_sizes, int n_in,
                              void* d_out, int out_size, void* d_ws, size_t ws_size,
                              hipStream_t stream){
  (void)in_sizes; (void)n_in; (void)out_size; (void)ws_size;
  const float* s_in  = (const float*)d_in[0];
  const float* pair  = (const float*)d_in[1];
  const float* qkv_w = (const float*)d_in[2];
  const float* qkv_b = (const float*)d_in[3];
  const float* out_w = (const float*)d_in[4];
  const float* out_b = (const float*)d_in[5];
  const float* fc1_w = (const float*)d_in[6];
  const float* fc1_b = (const float*)d_in[7];
  const float* fc2_w = (const float*)d_in[8];
  const float* fc2_b = (const float*)d_in[9];
  const float* ln_g  = (const float*)d_in[10];
  const float* ln_b  = (const float*)d_in[11];
  const float* pb_w  = (const float*)d_in[12];
  const float* pb_b  = (const float*)d_in[13];
  float* s = (float*)d_out;                    // residual stream lives in d_out

  char* ws = (char*)d_ws;
  size_t off = 0;
  auto take = [&](size_t bytes)->char*{
    char* p = ws + off; off += (bytes + 255) & ~(size_t)255; return p;
  };
  unsigned short* wqkv = (unsigned short*)take((size_t)NL_*3*D_*D_*2);
  unsigned short* wout = (unsigned short*)take((size_t)NL_*D_*D_*2);
  unsigned short* wfc1 = (unsigned short*)take((size_t)NL_*MLP_*D_*2);
  unsigned short* wfc2 = (unsigned short*)take((size_t)NL_*D_*MLP_*2);
  float*          bw   = (float*)take((size_t)NL_*B_*L_*W2_*4);
  unsigned short* hbf  = (unsigned short*)take((size_t)M_*D_*2);
  float*          qkvf = (float*)take((size_t)M_*3*D_*4);
  float*          q_r  = (float*)take((size_t)B_*H_*L_*DH_*4);
  float*          k_r  = (float*)take((size_t)B_*H_*L_*DH_*4);
  unsigned short* ybf  = (unsigned short*)take((size_t)M_*D_*2);
  unsigned short* gbf  = (unsigned short*)take((size_t)M_*MLP_*2);

  hipMemcpyAsync(s, s_in, (size_t)M_*D_*sizeof(float), hipMemcpyDeviceToDevice, stream);

  auto cvt = [&](const float* src, unsigned short* dst, size_t n){
    int n4 = (int)(n/4);
    cvt_bf16_k<<<(n4+255)/256, 256, 0, stream>>>(src, dst, n4);
  };
  cvt(qkv_w, wqkv, (size_t)NL_*3*D_*D_);
  cvt(out_w, wout, (size_t)NL_*D_*D_);
  cvt(fc1_w, wfc1, (size_t)NL_*MLP_*D_);
  cvt(fc2_w, wfc2, (size_t)NL_*D_*MLP_);

  pair_bias_k<<<(B_*L_*W2_ + 255)/256, 256, 0, stream>>>(pair, ln_g, ln_b, pb_w, pb_b, bw);

  for (int l=0; l<NL_; ++l){
    rmsnorm_k<<<M_, 256, 0, stream>>>(s, hbf);
    gemm_bt<0,128,1><<<dim3((3*D_)/128, M_/128), 256, 0, stream>>>(
        hbf, wqkv + (size_t)l*3*D_*D_, qkv_b + l*3*D_, qkvf, nullptr, nullptr, 3*D_, D_);
    rope_k<<<(B_*H_*L_*DH_)/256, 256, 0, stream>>>(qkvf, q_r, k_r);
    attn_k<<<dim3(L_/16, B_*H_), 256, 0, stream>>>(q_r, k_r, qkvf, bw, ybf, l);
    gemm_bt<1,64,2><<<dim3(D_/128, M_/64, 2), 256, 0, stream>>>(
        ybf, wout + (size_t)l*D_*D_, out_b + l*D_, nullptr, nullptr, s, D_, D_);
    rmsnorm_k<<<M_, 256, 0, stream>>>(s, hbf);
    gemm_bt<2,128,1><<<dim3(MLP_/128, M_/128), 256, 0, stream>>>(
        hbf, wfc1 + (size_t)l*MLP_*D_, fc1_b + l*MLP_, nullptr, gbf, nullptr, MLP_, D_);
    gemm_bt<3,64,4><<<dim3(D_/128, M_/64, 4), 256, 0, stream>>>(
        gbf, wfc2 + (size_t)l*D_*MLP_, fc2_b + l*D_, nullptr, nullptr, s, D_, MLP_);
  }
}